// Round 25
// baseline (131.695 us; speedup 1.0000x reference)
//
#include <hip/hip_runtime.h>
#include <stdint.h>

typedef __attribute__((ext_vector_type(8))) __bf16 bf16x8;
typedef __attribute__((ext_vector_type(4))) __bf16 bf16x4;
typedef __attribute__((ext_vector_type(8))) _Float16 f16x8;
typedef __attribute__((ext_vector_type(4))) float f32x4;
typedef __attribute__((ext_vector_type(4))) unsigned int u32x4;

#define SEQ 2048
#define LOG2E 1.4426950408889634f

// ---------- ws layout (bytes) ----------
#define OFF_AO    0ull               // bf16 [8192][512] (attn out)
#define OFF_WF    8388608ull         // fp16 [1536][512] (transposed QKV weights; Wq pre-scaled log2e)
#define OFF_WO    9961472ull         // bf16 [512][512]
#define OFF_Q     10485760ull        // fp16 [32][2048][64]
#define OFF_K     18874368ull        // fp16 [32][2048][64]
#define OFF_VT    27262976ull        // bf16 [32][64][2048] (s-permuted)
#define OFF_BIAS  35651584ull        // f32 [8][4096] (log2e-scaled)

__device__ __forceinline__ int swz(int row) { return ((row & 7) << 4) ^ ((row & 8) << 1); }

__device__ __forceinline__ void gl_lds16(const void* g, void* l) {
  __builtin_amdgcn_global_load_lds(
      (__attribute__((address_space(1))) void*)(uintptr_t)g,
      (__attribute__((address_space(3))) void*)(uint32_t)(uintptr_t)l, 16, 0, 0);
}

__device__ __forceinline__ float fast_exp2(float x) { return __builtin_amdgcn_exp2f(x); }

// ---------- prep: QKV weights fp16 (z<3) / Wo + bias table (z==3) ----------
__global__ void k_prep(const float* __restrict__ Wq, const float* __restrict__ Wk,
                       const float* __restrict__ Wv, const float* __restrict__ Wo,
                       const float* __restrict__ rel_bias,
                       _Float16* __restrict__ wf, __bf16* __restrict__ wo_t,
                       float* __restrict__ bias_tab) {
  int z = blockIdx.z;
  __shared__ float tile[64][65];
  const float* W = (z == 0) ? Wq : (z == 1) ? Wk : (z == 2) ? Wv : Wo;
  int k0 = blockIdx.y * 64, n0 = blockIdx.x * 64;
  int tx = threadIdx.x & 63, ty = threadIdx.x >> 6;
  for (int r = ty; r < 64; r += 4) tile[r][tx] = W[(size_t)(k0 + r) * 512 + n0 + tx];
  __syncthreads();
  if (z < 3) {
    float scale = (z == 0) ? LOG2E : 1.0f;
    for (int r = ty; r < 64; r += 4)
      wf[(size_t)(z * 512 + n0 + r) * 512 + k0 + tx] = (_Float16)(tile[tx][r] * scale);
  } else {
    for (int r = ty; r < 64; r += 4)
      wo_t[(size_t)(n0 + r) * 512 + k0 + tx] = (__bf16)tile[tx][r];
    int blk = blockIdx.y * 8 + blockIdx.x;
#pragma unroll
    for (int e = 0; e < 2; ++e) {
      int idx = blk * 512 + e * 256 + threadIdx.x;
      int h = idx >> 12, dIdx = idx & 4095;
      float v = 0.f;
      if (dIdx < 4095) {
        int d = dIdx - 2047;
        int rp = d < 0 ? -d : d;
        int bp;
        if (rp < 8) bp = rp;
        else bp = 8 + (rp >= 12) + (rp >= 16) + (rp >= 23) + (rp >= 32) + (rp >= 46) + (rp >= 64) + (rp >= 91);
        v = rel_bias[((d > 0 ? 16 : 0) + bp) * 8 + h] * LOG2E;
      }
      bias_tab[idx] = v;
    }
  }
}

// ---------- GEMM; MODE 0: fused f32->fp16 A-staging QKV (128x128 tiles);
// ----------        MODE 1: bf16 O-proj (128x64 tiles, 512 blocks = 2/CU) ----------
template <int MODE, int KSTEPS, int LDA, int LDB>
__global__ __launch_bounds__(256) void k_gemm(const void* __restrict__ Ap,
                                              const void* __restrict__ Btp,
                                              _Float16* __restrict__ qf,
                                              _Float16* __restrict__ kf,
                                              __bf16* __restrict__ vt,
                                              float* __restrict__ fo) {
  __shared__ __align__(16) char As[2][128 * 32 * 2];
  __shared__ __align__(16) char Bs[2][128 * 32 * 2];
  int tid = threadIdx.x, w = tid >> 6, l = tid & 63;
  int lr = l & 15, lh = l >> 4;
  int nwg = gridDim.x * gridDim.y;
  int flat = blockIdx.y * gridDim.x + blockIdx.x;
  int flat2 = (flat & 7) * (nwg >> 3) + (flat >> 3);
  constexpr int NTW = (MODE == 0) ? 128 : 64;       // n-tile width
  constexpr int NI = (MODE == 0) ? 4 : 2;           // 16-col fragments per wave
  int m0 = (flat2 / gridDim.x) * 128, n0 = (flat2 % gridDim.x) * NTW;
  int wm = (w >> 1) * 64;
  int wn = (MODE == 0) ? (w & 1) * 64 : (w & 1) * 32;
  f32x4 zero4 = {0.f, 0.f, 0.f, 0.f};
  f32x4 acc[4][NI];
#pragma unroll
  for (int i = 0; i < 4; ++i)
#pragma unroll
    for (int j = 0; j < NI; ++j) acc[i][j] = zero4;

  auto stage = [&](int kt, int buf) {
    if (MODE == 0) {
      const float* Af = (const float*)Ap;
#pragma unroll
      for (int c = 0; c < 2; ++c) {
        int i = c * 256 + tid;
        int row = i >> 2, cc = i & 3;
        const float* src = Af + (size_t)(m0 + row) * LDA + kt * 32 + cc * 8;
        float4 a = *(const float4*)src, b2 = *(const float4*)(src + 4);
        f16x8 hv;
        hv[0] = (_Float16)a.x;  hv[1] = (_Float16)a.y;
        hv[2] = (_Float16)a.z;  hv[3] = (_Float16)a.w;
        hv[4] = (_Float16)b2.x; hv[5] = (_Float16)b2.y;
        hv[6] = (_Float16)b2.z; hv[7] = (_Float16)b2.w;
        *(f16x8*)&As[buf][i * 16] = hv;
      }
#pragma unroll
      for (int c = 0; c < 2; ++c) {
        int i = c * 256 + tid;
        int row = i >> 2, cc = i & 3;
        gl_lds16((const char*)Btp + ((size_t)(n0 + row) * LDB + kt * 32 + cc * 8) * 2,
                 &Bs[buf][i * 16]);
      }
    } else {
#pragma unroll
      for (int c = 0; c < 2; ++c) {
        int i = c * 256 + tid;
        int row = i >> 2, cc = i & 3;
        gl_lds16((const char*)Ap + ((size_t)(m0 + row) * LDA + kt * 32 + cc * 8) * 2,
                 &As[buf][i * 16]);
      }
      {  // B: 64 rows only
        int i = tid;
        int row = i >> 2, cc = i & 3;
        gl_lds16((const char*)Btp + ((size_t)(n0 + row) * LDB + kt * 32 + cc * 8) * 2,
                 &Bs[buf][i * 16]);
      }
    }
  };

  stage(0, 0);
  __syncthreads();
#pragma unroll 2
  for (int kt = 0; kt < KSTEPS; ++kt) {
    int cur = kt & 1;
    if (kt + 1 < KSTEPS) stage(kt + 1, cur ^ 1);
    u32x4 af[4], bfr[NI];
#pragma unroll
    for (int mi = 0; mi < 4; ++mi)
      af[mi] = *(const u32x4*)&As[cur][((wm + mi * 16 + lr) * 32 + lh * 8) * 2];
#pragma unroll
    for (int ni = 0; ni < NI; ++ni)
      bfr[ni] = *(const u32x4*)&Bs[cur][((wn + ni * 16 + lr) * 32 + lh * 8) * 2];
#pragma unroll
    for (int mi = 0; mi < 4; ++mi)
#pragma unroll
      for (int ni = 0; ni < NI; ++ni) {
        if (MODE == 0)
          acc[mi][ni] = __builtin_amdgcn_mfma_f32_16x16x32_f16(
              __builtin_bit_cast(f16x8, af[mi]), __builtin_bit_cast(f16x8, bfr[ni]),
              acc[mi][ni], 0, 0, 0);
        else
          acc[mi][ni] = __builtin_amdgcn_mfma_f32_16x16x32_bf16(
              __builtin_bit_cast(bf16x8, af[mi]), __builtin_bit_cast(bf16x8, bfr[ni]),
              acc[mi][ni], 0, 0, 0);
      }
    __syncthreads();
  }

  if (MODE == 0 && n0 >= 1024) {
#pragma unroll
    for (int mi = 0; mi < 4; ++mi)
#pragma unroll
      for (int ni = 0; ni < NI; ++ni) {
        int m = m0 + wm + mi * 16 + lh * 4;
        int n = n0 + wn + ni * 16 + lr;
        int c9 = n & 511, hh = c9 >> 6, dh = c9 & 63;
        int b = m >> 11, s = m & 2047;
        int loc = s & 63;
        int pp = ((loc >> 5) << 5) | (((loc >> 2) & 3) << 3) | (((loc >> 4) & 1) << 2);
        bf16x4 o;
#pragma unroll
        for (int r = 0; r < 4; ++r) o[r] = (__bf16)acc[mi][ni][r];
        *(bf16x4*)&vt[((size_t)(b * 8 + hh) * 64 + dh) * 2048 + (s & ~63) + pp] = o;
      }
    return;
  }

#pragma unroll
  for (int mi = 0; mi < 4; ++mi)
#pragma unroll
    for (int ni = 0; ni < NI; ++ni)
#pragma unroll
      for (int r = 0; r < 4; ++r) {
        int m = m0 + wm + mi * 16 + lh * 4 + r;
        int n = n0 + wn + ni * 16 + lr;
        float vv = acc[mi][ni][r];
        if (MODE == 0) {
          int which = n >> 9, c9 = n & 511, hh = c9 >> 6, dh = c9 & 63;
          int b = m >> 11, s = m & 2047;
          size_t o = (size_t)((b * 8 + hh) * 2048 + s) * 64 + dh;
          if (which == 0) qf[o] = (_Float16)vv;
          else            kf[o] = (_Float16)vv;
        } else {
          fo[(size_t)m * 512 + n] = vv;
        }
      }
}

// ---------- flash attention: fp16 QK, QBLK=256, 8-buffer KV, barrier per 4 kt ----------
__global__ __launch_bounds__(512) void k_attn(const _Float16* __restrict__ qfp,
                                              const _Float16* __restrict__ kfp,
                                              const __bf16* __restrict__ vt,
                                              const float* __restrict__ bias_tab,
                                              __bf16* __restrict__ ao) {
  __shared__ __align__(16) char Ks[8][64 * 128];   // fp16 rows (64 elem * 2B)
  __shared__ __align__(16) char Vs[8][64 * 128];   // bf16 rows
  __shared__ float bias_s[2304];
  int tid = threadIdx.x, w = tid >> 6, l = tid & 63;
  int lr = l & 15, lh = l >> 4;
  int d = blockIdx.x;                              // 256 blocks (1/CU)
  int bh = (d & 7) + ((d >> 3) & 3) * 8;
  int q0 = (d >> 5) * 256;
  int h = bh & 7, b = bh >> 3;
  const char* kbase = (const char*)(kfp + (size_t)bh * SEQ * 64);
  const char* vbase = (const char*)(vt + (size_t)bh * 64 * SEQ);

  float bR = bias_tab[h * 4096 + 2047 + 200];
  float bL = bias_tab[h * 4096 + 2047 - 200];

  for (int j = tid; j < 2304; j += 512)
    bias_s[j] = bias_tab[h * 4096 + (1792 - q0) + j];

  auto stageKV = [&](int kt, int buf) {
    const char* kb = kbase + (size_t)kt * 64 * 128;
    const char* vb = vbase + (size_t)kt * 128;
    int row = tid >> 3, colb = (tid & 7) * 16;
    gl_lds16(kb + row * 128 + (colb ^ swz(row)), &Ks[buf][tid * 16]);
    gl_lds16(vb + (size_t)row * 4096 + (colb ^ swz(row)), &Vs[buf][tid * 16]);
  };

  // Q fragments (fp16, 2 q-sets of 16 rows) straight from global
  f16x8 qf[2][2];
#pragma unroll
  for (int qs = 0; qs < 2; ++qs) {
    int qrow = w * 32 + qs * 16 + lr;
    const _Float16* qg = qfp + ((size_t)bh * SEQ + q0 + qrow) * 64;
    qf[qs][0] = *(const f16x8*)(qg + lh * 8);
    qf[qs][1] = *(const f16x8*)(qg + 32 + lh * 8);
  }

  float l_run0 = 0.f, l_run1 = 0.f;
  f32x4 zero4 = {0.f, 0.f, 0.f, 0.f};
  f32x4 oacc[2][4];
#pragma unroll
  for (int qs = 0; qs < 2; ++qs)
#pragma unroll
    for (int i = 0; i < 4; ++i) oacc[qs][i] = zero4;

  // QK phase: bias C-init + 16 fp16 MFMAs into sacc
  auto qk = [&](int kt, int buf, f32x4 (&sacc)[2][4]) {
    int dmin = kt * 64 - q0 - 255, dmax = kt * 64 + 63 - q0;
    bool far = (dmin >= 91) || (dmax <= -91);
    f32x4 cinit[2][4];
    if (far) {
      float cb = (dmin >= 91) ? bR : bL;
#pragma unroll
      for (int qs = 0; qs < 2; ++qs)
#pragma unroll
        for (int t = 0; t < 4; ++t)
#pragma unroll
          for (int r = 0; r < 4; ++r) cinit[qs][t][r] = cb;
    } else {
#pragma unroll
      for (int qs = 0; qs < 2; ++qs) {
        int jb = kt * 64 + lh * 4 + 255 - (w * 32 + qs * 16 + lr);
#pragma unroll
        for (int t = 0; t < 4; ++t)
#pragma unroll
          for (int r = 0; r < 4; ++r) cinit[qs][t][r] = bias_s[jb + t * 16 + r];
      }
    }
    const char* kb = &Ks[buf][0];
    __builtin_amdgcn_s_setprio(1);
#pragma unroll
    for (int t = 0; t < 4; ++t) {
      int row = t * 16 + lr;
      f16x8 b0 = *(const f16x8*)(kb + row * 128 + ((lh * 16) ^ swz(row)));
      f16x8 b1 = *(const f16x8*)(kb + row * 128 + ((64 + lh * 16) ^ swz(row)));
#pragma unroll
      for (int qs = 0; qs < 2; ++qs) {
        f32x4 z = cinit[qs][t];
        z = __builtin_amdgcn_mfma_f32_16x16x32_f16(b0, qf[qs][0], z, 0, 0, 0);
        z = __builtin_amdgcn_mfma_f32_16x16x32_f16(b1, qf[qs][1], z, 0, 0, 0);
        sacc[qs][t] = z;
      }
    }
    __builtin_amdgcn_s_setprio(0);
  };

  // finish phase: static-shift softmax + bf16 PV
  auto finish = [&](int buf, f32x4 (&sacc)[2][4]) {
    bf16x8 paA[2], paB[2];
#pragma unroll
    for (int qs = 0; qs < 2; ++qs) {
      float p[4][4];
      float rt[4];
#pragma unroll
      for (int t = 0; t < 4; ++t) {
#pragma unroll
        for (int r = 0; r < 4; ++r) p[t][r] = fast_exp2(sacc[qs][t][r]);
        rt[t] = (p[t][0] + p[t][1]) + (p[t][2] + p[t][3]);
      }
      if (qs == 0) l_run0 += (rt[0] + rt[1]) + (rt[2] + rt[3]);
      else         l_run1 += (rt[0] + rt[1]) + (rt[2] + rt[3]);
      uint32_t pk[4][2];
#pragma unroll
      for (int t = 0; t < 4; ++t) {
        asm("v_cvt_pk_bf16_f32 %0, %1, %2" : "=v"(pk[t][0]) : "v"(p[t][0]), "v"(p[t][1]));
        asm("v_cvt_pk_bf16_f32 %0, %1, %2" : "=v"(pk[t][1]) : "v"(p[t][2]), "v"(p[t][3]));
      }
      u32x4 A0 = {pk[0][0], pk[0][1], pk[1][0], pk[1][1]};
      u32x4 A1 = {pk[2][0], pk[2][1], pk[3][0], pk[3][1]};
      paA[qs] = __builtin_bit_cast(bf16x8, A0);
      paB[qs] = __builtin_bit_cast(bf16x8, A1);
    }
    const char* vbr = &Vs[buf][0];
    __builtin_amdgcn_s_setprio(1);
#pragma unroll
    for (int ni = 0; ni < 4; ++ni) {
      int vrow = ni * 16 + lr;
      bf16x8 v0 = *(const bf16x8*)(vbr + vrow * 128 + ((lh * 16) ^ swz(vrow)));
      bf16x8 v1 = *(const bf16x8*)(vbr + vrow * 128 + ((64 + lh * 16) ^ swz(vrow)));
#pragma unroll
      for (int qs = 0; qs < 2; ++qs) {
        oacc[qs][ni] = __builtin_amdgcn_mfma_f32_16x16x32_bf16(paA[qs], v0, oacc[qs][ni], 0, 0, 0);
        oacc[qs][ni] = __builtin_amdgcn_mfma_f32_16x16x32_bf16(paB[qs], v1, oacc[qs][ni], 0, 0, 0);
      }
    }
    __builtin_amdgcn_s_setprio(0);
  };

  // 8-buffer pipeline, one barrier per 4 kt; group {rb..rb+3} computed while
  // {rb^4..} is staged; end-of-iter barrier protects the next overwrite.
  stageKV(0, 0);
  stageKV(1, 1);
  stageKV(2, 2);
  stageKV(3, 3);
  __syncthreads();
  f32x4 sA[2][4], sB[2][4];
#pragma unroll 2
  for (int kp = 0; kp < 8; ++kp) {
    int rb_ = (kp & 1) * 4;
    qk(4 * kp, rb_ + 0, sA);
    qk(4 * kp + 1, rb_ + 1, sB);
    if (kp < 7) {
      stageKV(4 * kp + 4, (rb_ ^ 4) + 0);
      stageKV(4 * kp + 5, (rb_ ^ 4) + 1);
    }
    finish(rb_ + 0, sA);
    finish(rb_ + 1, sB);
    qk(4 * kp + 2, rb_ + 2, sA);
    qk(4 * kp + 3, rb_ + 3, sB);
    if (kp < 7) {
      stageKV(4 * kp + 6, (rb_ ^ 4) + 2);
      stageKV(4 * kp + 7, (rb_ ^ 4) + 3);
    }
    finish(rb_ + 2, sA);
    finish(rb_ + 3, sB);
    __syncthreads();
  }

  // one-time class reduce of per-lane l partials
  l_run0 += __shfl_xor(l_run0, 16);
  l_run0 += __shfl_xor(l_run0, 32);
  l_run1 += __shfl_xor(l_run1, 16);
  l_run1 += __shfl_xor(l_run1, 32);

#pragma unroll
  for (int qs = 0; qs < 2; ++qs) {
    float lsel = (qs == 0) ? l_run0 : l_run1;
#pragma unroll
    for (int r = 0; r < 4; ++r) {
      float linv = 1.0f / __shfl(lsel, lh * 4 + r);
      int s = q0 + w * 32 + qs * 16 + lh * 4 + r;
#pragma unroll
      for (int ni = 0; ni < 4; ++ni) {
        int dh = ni * 16 + lr;
        ao[((size_t)(b * 2048 + s)) * 512 + h * 64 + dh] = (__bf16)(oacc[qs][ni][r] * linv);
      }
    }
  }
}

extern "C" void kernel_launch(void* const* d_in, const int* in_sizes, int n_in,
                              void* d_out, int out_size, void* d_ws, size_t ws_size,
                              hipStream_t stream) {
  (void)in_sizes; (void)n_in; (void)out_size; (void)ws_size;
  const float* hs = (const float*)d_in[0];
  const float* Wq = (const float*)d_in[1];
  const float* Wk = (const float*)d_in[2];
  const float* Wv = (const float*)d_in[3];
  const float* Wo = (const float*)d_in[4];
  const float* rb = (const float*)d_in[5];
  char* ws = (char*)d_ws;
  _Float16* wfb  = (_Float16*)(ws + OFF_WF);
  __bf16* wo_t   = (__bf16*)(ws + OFF_WO);
  _Float16* qfb  = (_Float16*)(ws + OFF_Q);
  _Float16* kfb  = (_Float16*)(ws + OFF_K);
  __bf16* vtb    = (__bf16*)(ws + OFF_VT);
  __bf16* aob    = (__bf16*)(ws + OFF_AO);
  float*  bias   = (float*)(ws + OFF_BIAS);

  k_prep<<<dim3(8, 8, 4), 256, 0, stream>>>(Wq, Wk, Wv, Wo, rb, wfb, wo_t, bias);
  k_gemm<0, 16, 512, 512><<<dim3(12, 64), 256, 0, stream>>>(hs, wfb, qfb, kfb, vtb, nullptr);
  k_attn<<<dim3(256), 512, 0, stream>>>(qfb, kfb, vtb, bias, aob);
  k_gemm<1, 16, 512, 512><<<dim3(8, 64), 256, 0, stream>>>(aob, wo_t, nullptr, nullptr, nullptr, (float*)d_out);
}

// Round 26
// 85.762 us; speedup vs baseline: 1.5356x; 1.5356x over previous
//
#include <hip/hip_runtime.h>
#include <stdint.h>

typedef __attribute__((ext_vector_type(8))) __bf16 bf16x8;
typedef __attribute__((ext_vector_type(4))) __bf16 bf16x4;
typedef __attribute__((ext_vector_type(8))) _Float16 f16x8;
typedef __attribute__((ext_vector_type(4))) float f32x4;
typedef __attribute__((ext_vector_type(4))) unsigned int u32x4;

#define SEQ 2048
#define LOG2E 1.4426950408889634f

// ---------- ws layout (bytes) ----------
#define OFF_AO    0ull               // bf16 [8192][512] (attn out)
#define OFF_WF    8388608ull         // fp16 [1536][512] (transposed QKV weights; Wq pre-scaled log2e)
#define OFF_WO    9961472ull         // bf16 [512][512]
#define OFF_Q     10485760ull        // fp16 [32][2048][64]
#define OFF_K     18874368ull        // fp16 [32][2048][64]
#define OFF_VT    27262976ull        // bf16 [32][64][2048] (s-permuted)
#define OFF_BIAS  35651584ull        // f32 [8][4096] (log2e-scaled)

__device__ __forceinline__ int swz(int row) { return ((row & 7) << 4) ^ ((row & 8) << 1); }

__device__ __forceinline__ void gl_lds16(const void* g, void* l) {
  __builtin_amdgcn_global_load_lds(
      (__attribute__((address_space(1))) void*)(uintptr_t)g,
      (__attribute__((address_space(3))) void*)(uint32_t)(uintptr_t)l, 16, 0, 0);
}

__device__ __forceinline__ float fast_exp2(float x) { return __builtin_amdgcn_exp2f(x); }

// ---------- prep: QKV weights fp16 (z<3) / Wo + bias table (z==3) ----------
__global__ void k_prep(const float* __restrict__ Wq, const float* __restrict__ Wk,
                       const float* __restrict__ Wv, const float* __restrict__ Wo,
                       const float* __restrict__ rel_bias,
                       _Float16* __restrict__ wf, __bf16* __restrict__ wo_t,
                       float* __restrict__ bias_tab) {
  int z = blockIdx.z;
  __shared__ float tile[64][65];
  const float* W = (z == 0) ? Wq : (z == 1) ? Wk : (z == 2) ? Wv : Wo;
  int k0 = blockIdx.y * 64, n0 = blockIdx.x * 64;
  int tx = threadIdx.x & 63, ty = threadIdx.x >> 6;
  for (int r = ty; r < 64; r += 4) tile[r][tx] = W[(size_t)(k0 + r) * 512 + n0 + tx];
  __syncthreads();
  if (z < 3) {
    float scale = (z == 0) ? LOG2E : 1.0f;
    for (int r = ty; r < 64; r += 4)
      wf[(size_t)(z * 512 + n0 + r) * 512 + k0 + tx] = (_Float16)(tile[tx][r] * scale);
  } else {
    for (int r = ty; r < 64; r += 4)
      wo_t[(size_t)(n0 + r) * 512 + k0 + tx] = (__bf16)tile[tx][r];
    int blk = blockIdx.y * 8 + blockIdx.x;
#pragma unroll
    for (int e = 0; e < 2; ++e) {
      int idx = blk * 512 + e * 256 + threadIdx.x;
      int h = idx >> 12, dIdx = idx & 4095;
      float v = 0.f;
      if (dIdx < 4095) {
        int d = dIdx - 2047;
        int rp = d < 0 ? -d : d;
        int bp;
        if (rp < 8) bp = rp;
        else bp = 8 + (rp >= 12) + (rp >= 16) + (rp >= 23) + (rp >= 32) + (rp >= 46) + (rp >= 64) + (rp >= 91);
        v = rel_bias[((d > 0 ? 16 : 0) + bp) * 8 + h] * LOG2E;
      }
      bias_tab[idx] = v;
    }
  }
}

// ---------- GEMM; MODE 0: fused f32->fp16 A-staging QKV (128x128 tiles);
// ----------        MODE 1: bf16 O-proj (128x64 tiles, 512 blocks = 2/CU) ----------
template <int MODE, int KSTEPS, int LDA, int LDB>
__global__ __launch_bounds__(256) void k_gemm(const void* __restrict__ Ap,
                                              const void* __restrict__ Btp,
                                              _Float16* __restrict__ qf,
                                              _Float16* __restrict__ kf,
                                              __bf16* __restrict__ vt,
                                              float* __restrict__ fo) {
  __shared__ __align__(16) char As[2][128 * 32 * 2];
  __shared__ __align__(16) char Bs[2][128 * 32 * 2];
  int tid = threadIdx.x, w = tid >> 6, l = tid & 63;
  int lr = l & 15, lh = l >> 4;
  int nwg = gridDim.x * gridDim.y;
  int flat = blockIdx.y * gridDim.x + blockIdx.x;
  int flat2 = (flat & 7) * (nwg >> 3) + (flat >> 3);
  constexpr int NTW = (MODE == 0) ? 128 : 64;       // n-tile width
  constexpr int NI = (MODE == 0) ? 4 : 2;           // 16-col fragments per wave
  int m0 = (flat2 / gridDim.x) * 128, n0 = (flat2 % gridDim.x) * NTW;
  int wm = (w >> 1) * 64;
  int wn = (MODE == 0) ? (w & 1) * 64 : (w & 1) * 32;
  f32x4 zero4 = {0.f, 0.f, 0.f, 0.f};
  f32x4 acc[4][NI];
#pragma unroll
  for (int i = 0; i < 4; ++i)
#pragma unroll
    for (int j = 0; j < NI; ++j) acc[i][j] = zero4;

  auto stage = [&](int kt, int buf) {
    if (MODE == 0) {
      const float* Af = (const float*)Ap;
#pragma unroll
      for (int c = 0; c < 2; ++c) {
        int i = c * 256 + tid;
        int row = i >> 2, cc = i & 3;
        const float* src = Af + (size_t)(m0 + row) * LDA + kt * 32 + cc * 8;
        float4 a = *(const float4*)src, b2 = *(const float4*)(src + 4);
        f16x8 hv;
        hv[0] = (_Float16)a.x;  hv[1] = (_Float16)a.y;
        hv[2] = (_Float16)a.z;  hv[3] = (_Float16)a.w;
        hv[4] = (_Float16)b2.x; hv[5] = (_Float16)b2.y;
        hv[6] = (_Float16)b2.z; hv[7] = (_Float16)b2.w;
        *(f16x8*)&As[buf][i * 16] = hv;
      }
#pragma unroll
      for (int c = 0; c < 2; ++c) {
        int i = c * 256 + tid;
        int row = i >> 2, cc = i & 3;
        gl_lds16((const char*)Btp + ((size_t)(n0 + row) * LDB + kt * 32 + cc * 8) * 2,
                 &Bs[buf][i * 16]);
      }
    } else {
#pragma unroll
      for (int c = 0; c < 2; ++c) {
        int i = c * 256 + tid;
        int row = i >> 2, cc = i & 3;
        gl_lds16((const char*)Ap + ((size_t)(m0 + row) * LDA + kt * 32 + cc * 8) * 2,
                 &As[buf][i * 16]);
      }
      {  // B: 64 rows only
        int i = tid;
        int row = i >> 2, cc = i & 3;
        gl_lds16((const char*)Btp + ((size_t)(n0 + row) * LDB + kt * 32 + cc * 8) * 2,
                 &Bs[buf][i * 16]);
      }
    }
  };

  stage(0, 0);
  __syncthreads();
#pragma unroll 2
  for (int kt = 0; kt < KSTEPS; ++kt) {
    int cur = kt & 1;
    if (kt + 1 < KSTEPS) stage(kt + 1, cur ^ 1);
    u32x4 af[4], bfr[NI];
#pragma unroll
    for (int mi = 0; mi < 4; ++mi)
      af[mi] = *(const u32x4*)&As[cur][((wm + mi * 16 + lr) * 32 + lh * 8) * 2];
#pragma unroll
    for (int ni = 0; ni < NI; ++ni)
      bfr[ni] = *(const u32x4*)&Bs[cur][((wn + ni * 16 + lr) * 32 + lh * 8) * 2];
#pragma unroll
    for (int mi = 0; mi < 4; ++mi)
#pragma unroll
      for (int ni = 0; ni < NI; ++ni) {
        if (MODE == 0)
          acc[mi][ni] = __builtin_amdgcn_mfma_f32_16x16x32_f16(
              __builtin_bit_cast(f16x8, af[mi]), __builtin_bit_cast(f16x8, bfr[ni]),
              acc[mi][ni], 0, 0, 0);
        else
          acc[mi][ni] = __builtin_amdgcn_mfma_f32_16x16x32_bf16(
              __builtin_bit_cast(bf16x8, af[mi]), __builtin_bit_cast(bf16x8, bfr[ni]),
              acc[mi][ni], 0, 0, 0);
      }
    __syncthreads();
  }

  if (MODE == 0 && n0 >= 1024) {
#pragma unroll
    for (int mi = 0; mi < 4; ++mi)
#pragma unroll
      for (int ni = 0; ni < NI; ++ni) {
        int m = m0 + wm + mi * 16 + lh * 4;
        int n = n0 + wn + ni * 16 + lr;
        int c9 = n & 511, hh = c9 >> 6, dh = c9 & 63;
        int b = m >> 11, s = m & 2047;
        int loc = s & 63;
        int pp = ((loc >> 5) << 5) | (((loc >> 2) & 3) << 3) | (((loc >> 4) & 1) << 2);
        bf16x4 o;
#pragma unroll
        for (int r = 0; r < 4; ++r) o[r] = (__bf16)acc[mi][ni][r];
        *(bf16x4*)&vt[((size_t)(b * 8 + hh) * 64 + dh) * 2048 + (s & ~63) + pp] = o;
      }
    return;
  }

#pragma unroll
  for (int mi = 0; mi < 4; ++mi)
#pragma unroll
    for (int ni = 0; ni < NI; ++ni)
#pragma unroll
      for (int r = 0; r < 4; ++r) {
        int m = m0 + wm + mi * 16 + lh * 4 + r;
        int n = n0 + wn + ni * 16 + lr;
        float vv = acc[mi][ni][r];
        if (MODE == 0) {
          int which = n >> 9, c9 = n & 511, hh = c9 >> 6, dh = c9 & 63;
          int b = m >> 11, s = m & 2047;
          size_t o = (size_t)((b * 8 + hh) * 2048 + s) * 64 + dh;
          if (which == 0) qf[o] = (_Float16)vv;
          else            kf[o] = (_Float16)vv;
        } else {
          fo[(size_t)m * 512 + n] = vv;
        }
      }
}

// ---------- flash attention: fp16 QK single-pass, QBLK=256, static-shift exp, 4-buffer ----------
__global__ __launch_bounds__(512) void k_attn(const _Float16* __restrict__ qfp,
                                              const _Float16* __restrict__ kfp,
                                              const __bf16* __restrict__ vt,
                                              const float* __restrict__ bias_tab,
                                              __bf16* __restrict__ ao) {
  __shared__ __align__(16) char Ks[4][64 * 128];   // fp16 rows (64 elem * 2B)
  __shared__ __align__(16) char Vs[4][64 * 128];   // bf16 rows
  __shared__ float bias_s[2304];
  int tid = threadIdx.x, w = tid >> 6, l = tid & 63;
  int lr = l & 15, lh = l >> 4;
  int d = blockIdx.x;                              // 256 blocks (1/CU)
  int bh = (d & 7) + ((d >> 3) & 3) * 8;
  int q0 = (d >> 5) * 256;
  int h = bh & 7, b = bh >> 3;
  const char* kbase = (const char*)(kfp + (size_t)bh * SEQ * 64);
  const char* vbase = (const char*)(vt + (size_t)bh * 64 * SEQ);

  float bR = bias_tab[h * 4096 + 2047 + 200];
  float bL = bias_tab[h * 4096 + 2047 - 200];

  for (int j = tid; j < 2304; j += 512)
    bias_s[j] = bias_tab[h * 4096 + (1792 - q0) + j];

  auto stageKV = [&](int kt, int buf) {
    const char* kb = kbase + (size_t)kt * 64 * 128;
    const char* vb = vbase + (size_t)kt * 128;
    int row = tid >> 3, colb = (tid & 7) * 16;
    gl_lds16(kb + row * 128 + (colb ^ swz(row)), &Ks[buf][tid * 16]);
    gl_lds16(vb + (size_t)row * 4096 + (colb ^ swz(row)), &Vs[buf][tid * 16]);
  };

  // Q fragments (fp16, 2 q-sets of 16 rows) straight from global
  f16x8 qf[2][2];
#pragma unroll
  for (int qs = 0; qs < 2; ++qs) {
    int qrow = w * 32 + qs * 16 + lr;
    const _Float16* qg = qfp + ((size_t)bh * SEQ + q0 + qrow) * 64;
    qf[qs][0] = *(const f16x8*)(qg + lh * 8);
    qf[qs][1] = *(const f16x8*)(qg + 32 + lh * 8);
  }

  float l_run0 = 0.f, l_run1 = 0.f;
  f32x4 zero4 = {0.f, 0.f, 0.f, 0.f};
  f32x4 oacc[2][4];
#pragma unroll
  for (int qs = 0; qs < 2; ++qs)
#pragma unroll
    for (int i = 0; i < 4; ++i) oacc[qs][i] = zero4;

  // QK phase: bias C-init + 16 fp16 MFMAs into sacc
  auto qk = [&](int kt, int buf, f32x4 (&sacc)[2][4]) {
    int dmin = kt * 64 - q0 - 255, dmax = kt * 64 + 63 - q0;
    bool far = (dmin >= 91) || (dmax <= -91);
    f32x4 cinit[2][4];
    if (far) {
      float cb = (dmin >= 91) ? bR : bL;
#pragma unroll
      for (int qs = 0; qs < 2; ++qs)
#pragma unroll
        for (int t = 0; t < 4; ++t)
#pragma unroll
          for (int r = 0; r < 4; ++r) cinit[qs][t][r] = cb;
    } else {
#pragma unroll
      for (int qs = 0; qs < 2; ++qs) {
        int jb = kt * 64 + lh * 4 + 255 - (w * 32 + qs * 16 + lr);
#pragma unroll
        for (int t = 0; t < 4; ++t)
#pragma unroll
          for (int r = 0; r < 4; ++r) cinit[qs][t][r] = bias_s[jb + t * 16 + r];
      }
    }
    const char* kb = &Ks[buf][0];
    __builtin_amdgcn_s_setprio(1);
#pragma unroll
    for (int t = 0; t < 4; ++t) {
      int row = t * 16 + lr;
      f16x8 b0 = *(const f16x8*)(kb + row * 128 + ((lh * 16) ^ swz(row)));
      f16x8 b1 = *(const f16x8*)(kb + row * 128 + ((64 + lh * 16) ^ swz(row)));
#pragma unroll
      for (int qs = 0; qs < 2; ++qs) {
        f32x4 z = cinit[qs][t];
        z = __builtin_amdgcn_mfma_f32_16x16x32_f16(b0, qf[qs][0], z, 0, 0, 0);
        z = __builtin_amdgcn_mfma_f32_16x16x32_f16(b1, qf[qs][1], z, 0, 0, 0);
        sacc[qs][t] = z;
      }
    }
    __builtin_amdgcn_s_setprio(0);
  };

  // finish phase: static-shift softmax + bf16 PV
  auto finish = [&](int buf, f32x4 (&sacc)[2][4]) {
    bf16x8 paA[2], paB[2];
#pragma unroll
    for (int qs = 0; qs < 2; ++qs) {
      float p[4][4];
      float rt[4];
#pragma unroll
      for (int t = 0; t < 4; ++t) {
#pragma unroll
        for (int r = 0; r < 4; ++r) p[t][r] = fast_exp2(sacc[qs][t][r]);
        rt[t] = (p[t][0] + p[t][1]) + (p[t][2] + p[t][3]);
      }
      if (qs == 0) l_run0 += (rt[0] + rt[1]) + (rt[2] + rt[3]);
      else         l_run1 += (rt[0] + rt[1]) + (rt[2] + rt[3]);
      uint32_t pk[4][2];
#pragma unroll
      for (int t = 0; t < 4; ++t) {
        asm("v_cvt_pk_bf16_f32 %0, %1, %2" : "=v"(pk[t][0]) : "v"(p[t][0]), "v"(p[t][1]));
        asm("v_cvt_pk_bf16_f32 %0, %1, %2" : "=v"(pk[t][1]) : "v"(p[t][2]), "v"(p[t][3]));
      }
      u32x4 A0 = {pk[0][0], pk[0][1], pk[1][0], pk[1][1]};
      u32x4 A1 = {pk[2][0], pk[2][1], pk[3][0], pk[3][1]};
      paA[qs] = __builtin_bit_cast(bf16x8, A0);
      paB[qs] = __builtin_bit_cast(bf16x8, A1);
    }
    const char* vbr = &Vs[buf][0];
    __builtin_amdgcn_s_setprio(1);
#pragma unroll
    for (int ni = 0; ni < 4; ++ni) {
      int vrow = ni * 16 + lr;
      bf16x8 v0 = *(const bf16x8*)(vbr + vrow * 128 + ((lh * 16) ^ swz(vrow)));
      bf16x8 v1 = *(const bf16x8*)(vbr + vrow * 128 + ((64 + lh * 16) ^ swz(vrow)));
#pragma unroll
      for (int qs = 0; qs < 2; ++qs) {
        oacc[qs][ni] = __builtin_amdgcn_mfma_f32_16x16x32_bf16(paA[qs], v0, oacc[qs][ni], 0, 0, 0);
        oacc[qs][ni] = __builtin_amdgcn_mfma_f32_16x16x32_bf16(paB[qs], v1, oacc[qs][ni], 0, 0, 0);
      }
    }
    __builtin_amdgcn_s_setprio(0);
  };

  // 4-buffer pipeline, one barrier per 2 kt; QK batches issued ahead of finishes
  stageKV(0, 0);
  stageKV(1, 1);
  __syncthreads();
  f32x4 sA[2][4], sB[2][4];
#pragma unroll 2
  for (int kp = 0; kp < 16; ++kp) {
    int rb_ = (kp & 1) * 2;
    qk(2 * kp, rb_, sA);
    qk(2 * kp + 1, rb_ + 1, sB);
    if (kp < 15) {
      stageKV(2 * kp + 2, rb_ ^ 2);
      stageKV(2 * kp + 3, (rb_ ^ 2) + 1);
    }
    finish(rb_, sA);
    finish(rb_ + 1, sB);
    __syncthreads();
  }

  // one-time class reduce of per-lane l partials
  l_run0 += __shfl_xor(l_run0, 16);
  l_run0 += __shfl_xor(l_run0, 32);
  l_run1 += __shfl_xor(l_run1, 16);
  l_run1 += __shfl_xor(l_run1, 32);

#pragma unroll
  for (int qs = 0; qs < 2; ++qs) {
    float lsel = (qs == 0) ? l_run0 : l_run1;
#pragma unroll
    for (int r = 0; r < 4; ++r) {
      float linv = 1.0f / __shfl(lsel, lh * 4 + r);
      int s = q0 + w * 32 + qs * 16 + lh * 4 + r;
#pragma unroll
      for (int ni = 0; ni < 4; ++ni) {
        int dh = ni * 16 + lr;
        ao[((size_t)(b * 2048 + s)) * 512 + h * 64 + dh] = (__bf16)(oacc[qs][ni][r] * linv);
      }
    }
  }
}

extern "C" void kernel_launch(void* const* d_in, const int* in_sizes, int n_in,
                              void* d_out, int out_size, void* d_ws, size_t ws_size,
                              hipStream_t stream) {
  (void)in_sizes; (void)n_in; (void)out_size; (void)ws_size;
  const float* hs = (const float*)d_in[0];
  const float* Wq = (const float*)d_in[1];
  const float* Wk = (const float*)d_in[2];
  const float* Wv = (const float*)d_in[3];
  const float* Wo = (const float*)d_in[4];
  const float* rb = (const float*)d_in[5];
  char* ws = (char*)d_ws;
  _Float16* wfb  = (_Float16*)(ws + OFF_WF);
  __bf16* wo_t   = (__bf16*)(ws + OFF_WO);
  _Float16* qfb  = (_Float16*)(ws + OFF_Q);
  _Float16* kfb  = (_Float16*)(ws + OFF_K);
  __bf16* vtb    = (__bf16*)(ws + OFF_VT);
  __bf16* aob    = (__bf16*)(ws + OFF_AO);
  float*  bias   = (float*)(ws + OFF_BIAS);

  k_prep<<<dim3(8, 8, 4), 256, 0, stream>>>(Wq, Wk, Wv, Wo, rb, wfb, wo_t, bias);
  k_gemm<0, 16, 512, 512><<<dim3(12, 64), 256, 0, stream>>>(hs, wfb, qfb, kfb, vtb, nullptr);
  k_attn<<<dim3(256), 512, 0, stream>>>(qfb, kfb, vtb, bias, aob);
  k_gemm<1, 16, 512, 512><<<dim3(8, 64), 256, 0, stream>>>(aob, wo_t, nullptr, nullptr, nullptr, (float*)d_out);
}